// Round 5
// baseline (3237.934 us; speedup 1.0000x reference)
//
#include <hip/hip_runtime.h>
#include <cstddef>

// Problem constants (fixed by the reference)
#define DEPTH  8
#define DIMM   1024
#define DI     2048      // d_inner
#define NST    16        // d_state
#define DCONVK 4
#define DTRANK 64
#define BB     2
#define LL     2048
#define MM     (BB*LL)   // 4096 rows
#define BD     (BB*DI)   // 4096 channels
#define CHK    32        // scan chunks
#define LC     (LL/CHK)  // 64 timesteps per chunk
#define LOG2E  1.44269504088896f

typedef __attribute__((ext_vector_type(8))) short bf16x8;
typedef __attribute__((ext_vector_type(4))) float f32x4;

// ================= fp32 -> bf16 plane split helpers =================
__device__ __forceinline__ unsigned short f2bf(float f) {
  unsigned int u = __float_as_uint(f);
  unsigned int r = (u + 0x7fffu + ((u >> 16) & 1u)) >> 16;   // RNE
  return (unsigned short)r;
}
__device__ __forceinline__ float bf2f(unsigned short h) {
  return __uint_as_float(((unsigned int)h) << 16);
}

// x[n] fp32 -> 2 planes (hi, lo) at p[0..n), p[n..2n)
__global__ __launch_bounds__(256) void cvt2_k(const float* __restrict__ x,
                                              unsigned short* __restrict__ p,
                                              size_t n) {
  size_t i = ((size_t)blockIdx.x * 256 + threadIdx.x) * 4;
  float4 v = *(const float4*)(x + i);
  float vv[4] = {v.x, v.y, v.z, v.w};
  unsigned short u1[4], u2[4];
#pragma unroll
  for (int k = 0; k < 4; ++k) {
    unsigned short h1 = f2bf(vv[k]);
    u1[k] = h1;
    u2[k] = f2bf(vv[k] - bf2f(h1));
  }
  *(ushort4*)(p + i)     = make_ushort4(u1[0], u1[1], u1[2], u1[3]);
  *(ushort4*)(p + n + i) = make_ushort4(u2[0], u2[1], u2[2], u2[3]);
}

// ===== 3-phase pipelined 3-product 2-plane bf16 MFMA GEMM: C = A*B^T =====
// BM=256; BN in {256,128}; optional split-K=2 (z-dim, separate outputs).
// Per K32-tile: ph0 = A0*B0, ph1 = A0*B1, ph2 = A1*B0; every vmcnt wait has
// >=2 phases of prefetch cover (2-phase merge regressed: 1-phase cover).
template <int BN, int NSPLIT>
__global__ __launch_bounds__(512, 2) void gemm3ph(
    const unsigned short* __restrict__ Ap, int lda_a, int pstr_a,
    const unsigned short* __restrict__ Bp, int lda_b, int pstr_b,
    float* __restrict__ C0, float* __restrict__ C1, int N, int Ktot) {
  constexpr int BM  = 256;
  constexpr int BF  = BN / 64;          // per-wave N-fragments (4 or 2)
  constexpr int BL  = BN / 128;         // B issues per plane (2 or 1)
  constexpr int RA1 = BM * 32;          // region offsets in shorts
  constexpr int RB0 = 2 * BM * 32;
  constexpr int RB1 = RB0 + BN * 32;
  constexpr int BUFS = (2 * BM + 2 * BN) * 32;   // shorts per buffer
  __shared__ unsigned short S[2 * BUFS];

  const int t  = threadIdx.x;
  const int w  = t >> 6;
  const int l  = t & 63;
  const int lm = l & 15;
  const int qs = ((l >> 4) << 3) ^ (((lm >> 1) & 3) << 3);

  // T1: XCD-aware bijective block swizzle (nwg % 8 == 0 in both uses)
  const int nx   = gridDim.x;
  const int nwg  = nx * gridDim.y;
  const int flat = blockIdx.y * nx + blockIdx.x;
  const int swz  = (flat & 7) * (nwg >> 3) + (flat >> 3);
  const int m0 = (swz / nx) * BM;
  const int n0 = (swz % nx) * BN;
  const int z  = (NSPLIT == 2) ? blockIdx.z : 0;
  const int KS = Ktot / NSPLIT;

  const int wm = (w & 1) << 7;          // 0 / 128
  const int wn = (w >> 1) * (BN / 4);   // 4 N-waves

  const int rr = t >> 2;
  const int kq = ((t & 3) ^ ((rr >> 1) & 3)) << 3;
  const unsigned short* srcA = Ap + (size_t)(m0 + rr) * lda_a + (size_t)z * KS + kq;
  const unsigned short* srcB = Bp + (size_t)(n0 + rr) * lda_b + (size_t)z * KS + kq;
  const size_t a128 = (size_t)128 * lda_a;
  const size_t b128 = (size_t)128 * lda_b;
  const int dbase = (w << 6) * 8;       // wave-uniform dst base (shorts)

#define GI(p_, off_)                                                           \
  __builtin_amdgcn_global_load_lds(                                            \
      (const __attribute__((address_space(1))) unsigned int*)(p_),             \
      (__attribute__((address_space(3))) unsigned int*)&S[bnext + (off_) + dbase], \
      16, 0, 0)

#define GI_PH0(kb_)                                                            \
  { GI(srcA + (kb_), 0); GI(srcA + a128 + (kb_), 4096);                        \
    GI(srcB + (kb_), RB0);                                                     \
    if constexpr (BL == 2) GI(srcB + b128 + (kb_), RB0 + 4096); }

#define GI_PH1(kb_)                                                            \
  { GI(srcB + (size_t)pstr_b + (kb_), RB1);                                    \
    if constexpr (BL == 2) GI(srcB + (size_t)pstr_b + b128 + (kb_), RB1 + 4096); }

#define GI_PH2(kb_)                                                            \
  { GI(srcA + (size_t)pstr_a + (kb_), RA1);                                    \
    GI(srcA + (size_t)pstr_a + a128 + (kb_), RA1 + 4096); }

  f32x4 acc[8][BF];
#pragma unroll
  for (int i = 0; i < 8; ++i)
#pragma unroll
    for (int j = 0; j < BF; ++j) acc[i][j] = (f32x4){0.f, 0.f, 0.f, 0.f};

  { // prologue: stage tile 0 into buf0; queue order A0,B0 | B1 | A1
    const int bnext = 0;
    GI_PH0((size_t)0);
    GI_PH1((size_t)0);
    GI_PH2((size_t)0);
  }
  if constexpr (BN == 256) asm volatile("s_waitcnt vmcnt(4)" ::: "memory");
  else                     asm volatile("s_waitcnt vmcnt(3)" ::: "memory");
  __builtin_amdgcn_s_barrier();

  const int NT = KS >> 5;
#pragma unroll 2
  for (int ti = 0; ti < NT; ++ti) {
    const int bcur  = (ti & 1) ? BUFS : 0;
    const int bnext = (ti & 1) ? 0 : BUFS;
    const size_t kb = (size_t)((ti + 1 < NT) ? (ti + 1) : 0) * 32; // dummy tail prefetch
    const unsigned short* Sb = &S[bcur];
    bf16x8 a[8], b0[BF], b1[BF];

    // ---- phase 0: A0 x B0 ----
#pragma unroll
    for (int i = 0; i < 8; ++i)
      a[i] = *(const bf16x8*)&Sb[(wm + i * 16 + lm) * 32 + qs];
#pragma unroll
    for (int j = 0; j < BF; ++j)
      b0[j] = *(const bf16x8*)&Sb[RB0 + (wn + j * 16 + lm) * 32 + qs];
    GI_PH0(kb);
    if constexpr (BN == 256) asm volatile("s_waitcnt vmcnt(6)" ::: "memory");
    else                     asm volatile("s_waitcnt vmcnt(5)" ::: "memory");
    __builtin_amdgcn_s_barrier();
    asm volatile("s_waitcnt lgkmcnt(0)" ::: "memory");
    __builtin_amdgcn_s_setprio(1);
#pragma unroll
    for (int i = 0; i < 8; ++i)
#pragma unroll
      for (int j = 0; j < BF; ++j)
        acc[i][j] = __builtin_amdgcn_mfma_f32_16x16x32_bf16(a[i], b0[j], acc[i][j], 0, 0, 0);
    __builtin_amdgcn_s_setprio(0);
    __builtin_amdgcn_s_barrier();

    // ---- phase 1: A0 x B1 ----
#pragma unroll
    for (int j = 0; j < BF; ++j)
      b1[j] = *(const bf16x8*)&Sb[RB1 + (wn + j * 16 + lm) * 32 + qs];
    GI_PH1(kb);
    if constexpr (BN == 256) asm volatile("s_waitcnt vmcnt(6)" ::: "memory");
    else                     asm volatile("s_waitcnt vmcnt(4)" ::: "memory");
    __builtin_amdgcn_s_barrier();
    asm volatile("s_waitcnt lgkmcnt(0)" ::: "memory");
    __builtin_amdgcn_s_setprio(1);
#pragma unroll
    for (int i = 0; i < 8; ++i)
#pragma unroll
      for (int j = 0; j < BF; ++j)
        acc[i][j] = __builtin_amdgcn_mfma_f32_16x16x32_bf16(a[i], b1[j], acc[i][j], 0, 0, 0);
    __builtin_amdgcn_s_setprio(0);
    __builtin_amdgcn_s_barrier();

    // ---- phase 2: A1 x B0 ----
#pragma unroll
    for (int i = 0; i < 8; ++i)
      a[i] = *(const bf16x8*)&Sb[RA1 + (wm + i * 16 + lm) * 32 + qs];
    GI_PH2(kb);
    if constexpr (BN == 256) asm volatile("s_waitcnt vmcnt(4)" ::: "memory");
    else                     asm volatile("s_waitcnt vmcnt(3)" ::: "memory");
    __builtin_amdgcn_s_barrier();
    asm volatile("s_waitcnt lgkmcnt(0)" ::: "memory");
    __builtin_amdgcn_s_setprio(1);
#pragma unroll
    for (int i = 0; i < 8; ++i)
#pragma unroll
      for (int j = 0; j < BF; ++j)
        acc[i][j] = __builtin_amdgcn_mfma_f32_16x16x32_bf16(a[i], b0[j], acc[i][j], 0, 0, 0);
    __builtin_amdgcn_s_setprio(0);
    __builtin_amdgcn_s_barrier();
  }
#undef GI_PH2
#undef GI_PH1
#undef GI_PH0
#undef GI

  float* Cc = (NSPLIT == 2 && blockIdx.z) ? C1 : C0;
  const int row0 = (l >> 4) << 2;
#pragma unroll
  for (int i = 0; i < 8; ++i)
#pragma unroll
    for (int j = 0; j < BF; ++j)
#pragma unroll
      for (int r = 0; r < 4; ++r) {
        int m = m0 + wm + i * 16 + row0 + r;
        int n = n0 + wn + j * 16 + lm;
        Cc[(size_t)m * N + n] = acc[i][j][r];
      }
}

// ------- dt_proj via MFMA planes, fused bias+softplus -------
__global__ __launch_bounds__(256) void dtproj_mp(const unsigned short* __restrict__ Ap,
                                                 const unsigned short* __restrict__ Bp,
                                                 const float* __restrict__ bdt,
                                                 float* __restrict__ Cd) {
  __shared__ unsigned short S[32768];   // 2 ktiles x (2 planes A + 2 planes B) x 128 x 32
  const int t  = threadIdx.x;
  const int w  = t >> 6;
  const int l  = t & 63;
  const int lm = l & 15;
  const int q8 = (l >> 4) << 3;
  const int qs = q8 ^ (((lm >> 1) & 3) << 3);
  const int m0 = blockIdx.y * 128;
  const int n0 = blockIdx.x * 128;
  const int wm = (w & 1) << 6;
  const int wn = (w >> 1) << 6;

#pragma unroll
  for (int it = 0; it < 16; ++it) {
    int c  = it * 256 + t;
    int kt = c >> 11;
    int c2 = c & 2047;
    const unsigned short* base;
    int r, aslot;
    if (c2 < 1024) {
      int p = c2 >> 9; int wi = c2 & 511; r = wi >> 2; aslot = wi & 3;
      base = Ap + (size_t)p * (MM * 64) + (size_t)(m0 + r) * 64;
    } else {
      int c3 = c2 - 1024;
      int p = c3 >> 9; int wi = c3 & 511; r = wi >> 2; aslot = wi & 3;
      base = Bp + (size_t)p * (DI * 64) + (size_t)(n0 + r) * 64;
    }
    int kq = (aslot ^ ((r >> 1) & 3)) << 3;
    __builtin_amdgcn_global_load_lds(
        (const __attribute__((address_space(1))) unsigned int*)(base + kt * 32 + kq),
        (__attribute__((address_space(3))) unsigned int*)&S[(size_t)(it * 256 + (w << 6)) * 8],
        16, 0, 0);
  }
  __syncthreads();

  f32x4 acc[4][4];
#pragma unroll
  for (int i = 0; i < 4; ++i)
#pragma unroll
    for (int j = 0; j < 4; ++j) acc[i][j] = (f32x4){0.f, 0.f, 0.f, 0.f};

#pragma unroll
  for (int kt = 0; kt < 2; ++kt) {
    const int RA = kt * 16384;          // A plane0 region (shorts)
    const int RB = kt * 16384 + 8192;   // B plane0 region
    bf16x8 a0[4], aX[4], b0[4];
#pragma unroll
    for (int i = 0; i < 4; ++i)
      a0[i] = *(const bf16x8*)&S[RA + (wm + i * 16 + lm) * 32 + qs];
#pragma unroll
    for (int j = 0; j < 4; ++j)
      b0[j] = *(const bf16x8*)&S[RB + (wn + j * 16 + lm) * 32 + qs];
#pragma unroll
    for (int i = 0; i < 4; ++i)
#pragma unroll
      for (int j = 0; j < 4; ++j)
        acc[i][j] = __builtin_amdgcn_mfma_f32_16x16x32_bf16(a0[i], b0[j], acc[i][j], 0, 0, 0);
#pragma unroll
    for (int j = 0; j < 4; ++j)        // B plane 1
      aX[j] = *(const bf16x8*)&S[RB + 4096 + (wn + j * 16 + lm) * 32 + qs];
#pragma unroll
    for (int i = 0; i < 4; ++i)
#pragma unroll
      for (int j = 0; j < 4; ++j)
        acc[i][j] = __builtin_amdgcn_mfma_f32_16x16x32_bf16(a0[i], aX[j], acc[i][j], 0, 0, 0);
#pragma unroll
    for (int i = 0; i < 4; ++i)        // A plane 1
      aX[i] = *(const bf16x8*)&S[RA + 4096 + (wm + i * 16 + lm) * 32 + qs];
#pragma unroll
    for (int i = 0; i < 4; ++i)
#pragma unroll
      for (int j = 0; j < 4; ++j)
        acc[i][j] = __builtin_amdgcn_mfma_f32_16x16x32_bf16(aX[i], b0[j], acc[i][j], 0, 0, 0);
  }

  const int row0 = (l >> 4) << 2;
#pragma unroll
  for (int j = 0; j < 4; ++j) {
    int n = n0 + wn + j * 16 + lm;
    float bv = bdt[n];
#pragma unroll
    for (int i = 0; i < 4; ++i)
#pragma unroll
      for (int r = 0; r < 4; ++r) {
        int m = m0 + wm + i * 16 + row0 + r;
        float x = acc[i][j][r] + bv;
        Cd[(size_t)m * DI + n] = fmaxf(x, 0.f) + log1pf(expf(-fabsf(x)));
      }
  }
}

// ---------------- x_proj split-K: C[4096,96] = xc * Wx^T ----------------
#define XPN 96
__global__ __launch_bounds__(256) void xproj_part_k(const float* __restrict__ A,
                                                    const float* __restrict__ W,
                                                    float* __restrict__ Cp) {
  __shared__ float As[16][128];
  __shared__ float Ws[16][XPN];
  const int t  = threadIdx.x;
  const int tx = t & 15;
  const int ty = t >> 4;
  const int m0 = blockIdx.x * 128;
  const int kb = blockIdx.y * 256;
  float acc[8][6];
#pragma unroll
  for (int i = 0; i < 8; ++i)
#pragma unroll
    for (int j = 0; j < 6; ++j) acc[i][j] = 0.f;

  for (int k0 = kb; k0 < kb + 256; k0 += 16) {
#pragma unroll
    for (int e = t; e < 512; e += 256) {
      int r = e >> 2, cq = (e & 3) << 2;
      float4 v = *(const float4*)(A + (size_t)(m0 + r) * DI + k0 + cq);
      As[cq+0][r] = v.x; As[cq+1][r] = v.y; As[cq+2][r] = v.z; As[cq+3][r] = v.w;
    }
    for (int e = t; e < 384; e += 256) {
      int r = e >> 2, cq = (e & 3) << 2;
      float4 v = *(const float4*)(W + (size_t)r * DI + k0 + cq);
      Ws[cq+0][r] = v.x; Ws[cq+1][r] = v.y; Ws[cq+2][r] = v.z; Ws[cq+3][r] = v.w;
    }
    __syncthreads();
#pragma unroll
    for (int kk = 0; kk < 16; ++kk) {
      float a[8], b[6];
#pragma unroll
      for (int i = 0; i < 8; ++i) a[i] = As[kk][ty*8 + i];
#pragma unroll
      for (int j = 0; j < 6; ++j) b[j] = Ws[kk][tx*6 + j];
#pragma unroll
      for (int i = 0; i < 8; ++i)
#pragma unroll
        for (int j = 0; j < 6; ++j) acc[i][j] += a[i] * b[j];
    }
    __syncthreads();
  }
  float* cp = Cp + (size_t)blockIdx.y * MM * XPN;
#pragma unroll
  for (int i = 0; i < 8; ++i)
#pragma unroll
    for (int j = 0; j < 6; ++j)
      cp[(size_t)(m0 + ty*8 + i) * XPN + tx*6 + j] = acc[i][j];
}

// reduce partials -> fp32 xdbl; dt columns (0..63) also emitted as 2 bf16 planes
__global__ __launch_bounds__(256) void xproj_red_k(const float* __restrict__ Cp,
                                                   float* __restrict__ o,
                                                   unsigned short* __restrict__ dtp) {
  int i = blockIdx.x * 256 + threadIdx.x;    // MM*96
  float s = 0.f;
#pragma unroll
  for (int ks = 0; ks < 8; ++ks) s += Cp[(size_t)ks * (MM * XPN) + i];
  o[i] = s;
  int m = i / 96, col = i - m * 96;
  if (col < DTRANK) {
    unsigned short h1 = f2bf(s);
    dtp[(size_t)m * DTRANK + col] = h1;
    dtp[(size_t)MM * DTRANK + (size_t)m * DTRANK + col] = f2bf(s - bf2f(h1));
  }
}

__device__ __forceinline__ float fast_silu(float x) {
  return x * __builtin_amdgcn_rcpf(1.f + exp2f(-LOG2E * x));
}

// ---------------- depthwise causal conv1d + SiLU ----------------
__global__ __launch_bounds__(256) void conv_silu_k(const float* __restrict__ xz,
                                                   const float* __restrict__ cw,
                                                   const float* __restrict__ cb,
                                                   float* __restrict__ xc) {
  int idx = blockIdx.x * 256 + threadIdx.x;
  int c  = idx & (DI - 1);
  int bl = idx >> 11;
  int l  = bl & (LL - 1);
  float acc = cb[c];
#pragma unroll
  for (int k = 0; k < DCONVK; ++k) {
    int ls = l - (DCONVK - 1) + k;
    if (ls >= 0)
      acc += xz[(size_t)(bl - (DCONVK - 1) + k) * (2*DI) + c] * cw[c*DCONVK + k];
  }
  xc[idx] = fast_silu(acc);
}

// ======================= chunked selective scan =======================
// Per-channel threads: one thread owns ONE channel for one chunk, all 16
// states in registers. Loads (delta/xc/z) are 1x and coalesced (consecutive
// threads = consecutive d); B/C rows are wave-uniform LDS broadcasts; the
// C-dot-h reduction is 16 in-thread FMAs (no shuffles); y stores all-lane
// coalesced. Replaces the 4-lanes-per-channel layout whose address-dup +
// shuffles + 1/4-active stores made the scans ~7x off their VALU roofline.
__global__ __launch_bounds__(256) void scan_pass1(const float* __restrict__ delta,
                                                  const float* __restrict__ xc,
                                                  const float* __restrict__ xdbl,
                                                  const float* __restrict__ A_log,
                                                  float* __restrict__ Hc,
                                                  float* __restrict__ Sdt) {
  const int t  = threadIdx.x;
  const int g  = blockIdx.x;          // 16 channel groups of 256
  const int c  = blockIdx.y;          // 32 chunks
  const int ch = g * 256 + t;
  const int b  = ch >> 11;            // block-uniform (256 | 2048)
  const int d  = ch & (DI - 1);
  const size_t rowbase = (size_t)b * LL + (size_t)c * LC;

  __shared__ float Bs[LC * 16];   // 4KB: B rows of this chunk
  { int row = t >> 2, seg = t & 3;
    *(float4*)&Bs[row * 16 + seg * 4] =
        *(const float4*)(xdbl + (rowbase + row) * 96 + DTRANK + seg * 4);
  }
  __syncthreads();

  float Av[NST];
#pragma unroll
  for (int n4 = 0; n4 < 4; ++n4) {
    float4 al = *(const float4*)(A_log + (size_t)d * NST + n4 * 4);
    Av[n4*4+0] = -expf(al.x) * LOG2E;
    Av[n4*4+1] = -expf(al.y) * LOG2E;
    Av[n4*4+2] = -expf(al.z) * LOG2E;
    Av[n4*4+3] = -expf(al.w) * LOG2E;
  }
  float h[NST];
#pragma unroll
  for (int n = 0; n < NST; ++n) h[n] = 0.f;
  float S = 0.f;

#define P1_SU 4
  float aD[P1_SU], aX[P1_SU];
  float bD[P1_SU], bX[P1_SU];

#define P1_LOAD(l0, D_, X_)                                            \
  { _Pragma("unroll")                                                  \
    for (int u = 0; u < P1_SU; ++u) {                                  \
      size_t bl = rowbase + (l0) + u;                                  \
      D_[u] = delta[bl * DI + d];                                      \
      X_[u] = xc[bl * DI + d];                                         \
    } }

#define P1_COMP(l0, D_, X_)                                            \
  { _Pragma("unroll")                                                  \
    for (int u = 0; u < P1_SU; ++u) {                                  \
      float dt = D_[u], uB = dt * X_[u];                               \
      const f32x4* B4 = (const f32x4*)&Bs[((l0) + u) * 16];            \
      f32x4 B0 = B4[0], B1 = B4[1], B2 = B4[2], B3 = B4[3];            \
      _Pragma("unroll")                                                \
      for (int n = 0; n < 4; ++n) {                                    \
        h[n]      = fmaf(exp2f(dt * Av[n]),      h[n],      uB * B0[n]); \
        h[4 + n]  = fmaf(exp2f(dt * Av[4 + n]),  h[4 + n],  uB * B1[n]); \
        h[8 + n]  = fmaf(exp2f(dt * Av[8 + n]),  h[8 + n],  uB * B2[n]); \
        h[12 + n] = fmaf(exp2f(dt * Av[12 + n]), h[12 + n], uB * B3[n]); \
      }                                                                \
      S += dt;                                                         \
    } }

  P1_LOAD(0, aD, aX);
  for (int l0 = 0; l0 < LC; l0 += 2 * P1_SU) {
    P1_LOAD(l0 + P1_SU, bD, bX);
    P1_COMP(l0, aD, aX);
    if (l0 + 2 * P1_SU < LC) P1_LOAD(l0 + 2 * P1_SU, aD, aX);
    P1_COMP(l0 + P1_SU, bD, bX);
  }
#undef P1_LOAD
#undef P1_COMP

  float* hp = Hc + ((size_t)c * BD + ch) * NST;
#pragma unroll
  for (int n4 = 0; n4 < 4; ++n4)
    *(float4*)(hp + n4 * 4) =
        make_float4(h[n4*4], h[n4*4+1], h[n4*4+2], h[n4*4+3]);
  Sdt[(size_t)c * BD + ch] = S;
}

__global__ __launch_bounds__(256) void scan_pass2(float* __restrict__ Hc,
                                                  const float* __restrict__ Sdt,
                                                  const float* __restrict__ A_log) {
  const int g  = blockIdx.x * 256 + threadIdx.x;
  const int n  = g & (NST - 1);
  const int ch = g >> 4;
  const int d  = ch & (DI - 1);
  const float Av2 = -expf(A_log[d * NST + n]) * LOG2E;
  float Sv[CHK];
#pragma unroll
  for (int c = 0; c < CHK; ++c) Sv[c] = Sdt[(size_t)c * BD + ch];
  float h = 0.f;
  float tmp = Hc[(size_t)ch * NST + n];
#pragma unroll
  for (int c = 0; c < CHK; ++c) {
    size_t idx = ((size_t)c * BD + ch) * NST + n;
    float tnext = (c + 1 < CHK) ? Hc[((size_t)(c+1) * BD + ch) * NST + n] : 0.f;
    Hc[idx] = h;
    h = fmaf(exp2f(Av2 * Sv[c]), h, tmp);
    tmp = tnext;
  }
}

// pass3: re-scan from true start state, per-channel threads; emits gated y
// as 2 bf16 planes via coalesced all-lane ushort stores into xz's xs-half.
__global__ __launch_bounds__(256) void scan_pass3(const float* __restrict__ delta,
                                                  const float* __restrict__ xc,
                                                  const float* __restrict__ xdbl,
                                                  const float* __restrict__ A_log,
                                                  float* __restrict__ xzp,
                                                  const float* __restrict__ Dp,
                                                  const float* __restrict__ Hc) {
  const int t  = threadIdx.x;
  const int g  = blockIdx.x;
  const int c  = blockIdx.y;
  const int ch = g * 256 + t;
  const int b  = ch >> 11;
  const int d  = ch & (DI - 1);
  const size_t rowbase = (size_t)b * LL + (size_t)c * LC;

  __shared__ float BCs[LC * 32];  // 8KB: B|C rows of this chunk
  {
#pragma unroll
    for (int e = t; e < 512; e += 256) {
      int row = e >> 3, seg = e & 7;
      *(float4*)&BCs[row * 32 + seg * 4] =
          *(const float4*)(xdbl + (rowbase + row) * 96 + DTRANK + seg * 4);
    }
  }
  __syncthreads();

  float Av[NST];
#pragma unroll
  for (int n4 = 0; n4 < 4; ++n4) {
    float4 al = *(const float4*)(A_log + (size_t)d * NST + n4 * 4);
    Av[n4*4+0] = -expf(al.x) * LOG2E;
    Av[n4*4+1] = -expf(al.y) * LOG2E;
    Av[n4*4+2] = -expf(al.z) * LOG2E;
    Av[n4*4+3] = -expf(al.w) * LOG2E;
  }
  const float Dv = Dp[d];
  float h[NST];
  { const float* hp = Hc + ((size_t)c * BD + ch) * NST;
#pragma unroll
    for (int n4 = 0; n4 < 4; ++n4) {
      float4 hv = *(const float4*)(hp + n4 * 4);
      h[n4*4+0] = hv.x; h[n4*4+1] = hv.y; h[n4*4+2] = hv.z; h[n4*4+3] = hv.w;
    }
  }
  unsigned short* yp = (unsigned short*)xzp;

#define P3_SU 2
  float aD[P3_SU], aX[P3_SU], aZ[P3_SU];
  float bD[P3_SU], bX[P3_SU], bZ[P3_SU];

#define P3_LOAD(l0, D_, X_, Z_)                                        \
  { _Pragma("unroll")                                                  \
    for (int u = 0; u < P3_SU; ++u) {                                  \
      size_t bl = rowbase + (l0) + u;                                  \
      D_[u] = delta[bl * DI + d];                                      \
      X_[u] = xc[bl * DI + d];                                         \
      Z_[u] = xzp[bl * (2*DI) + DI + d];                               \
    } }

#define P3_COMP(l0, D_, X_, Z_)                                        \
  { _Pragma("unroll")                                                  \
    for (int u = 0; u < P3_SU; ++u) {                                  \
      float dt = D_[u], uB = dt * X_[u];                               \
      const f32x4* R4 = (const f32x4*)&BCs[((l0) + u) * 32];           \
      f32x4 B0 = R4[0], B1 = R4[1], B2 = R4[2], B3 = R4[3];            \
      f32x4 C0 = R4[4], C1 = R4[5], C2 = R4[6], C3 = R4[7];            \
      _Pragma("unroll")                                                \
      for (int n = 0; n < 4; ++n) {                                    \
        h[n]      = fmaf(exp2f(dt * Av[n]),      h[n],      uB * B0[n]); \
        h[4 + n]  = fmaf(exp2f(dt * Av[4 + n]),  h[4 + n],  uB * B1[n]); \
        h[8 + n]  = fmaf(exp2f(dt * Av[8 + n]),  h[8 + n],  uB * B2[n]); \
        h[12 + n] = fmaf(exp2f(dt * Av[12 + n]), h[12 + n], uB * B3[n]); \
      }                                                                \
      /* same fma tree as the old shuffle reduction: bit-identical */  \
      float p0 = fmaf(h[1],  C0[1], h[0]  * C0[0]);                    \
      p0 += fmaf(h[3],  C0[3], h[2]  * C0[2]);                         \
      float p1 = fmaf(h[5],  C1[1], h[4]  * C1[0]);                    \
      p1 += fmaf(h[7],  C1[3], h[6]  * C1[2]);                         \
      float p2 = fmaf(h[9],  C2[1], h[8]  * C2[0]);                    \
      p2 += fmaf(h[11], C2[3], h[10] * C2[2]);                         \
      float p3 = fmaf(h[13], C3[1], h[12] * C3[0]);                    \
      p3 += fmaf(h[15], C3[3], h[14] * C3[2]);                         \
      float s = (p0 + p1) + (p2 + p3);                                 \
      float yv = (s + X_[u] * Dv) * fast_silu(Z_[u]);                  \
      unsigned short y1 = f2bf(yv);                                    \
      size_t yb = (rowbase + (l0) + u) * 8192 + d;                     \
      yp[yb] = y1;                                                     \
      yp[yb + 2048] = f2bf(yv - bf2f(y1));                             \
    } }

  P3_LOAD(0, aD, aX, aZ);
  for (int l0 = 0; l0 < LC; l0 += 2 * P3_SU) {
    P3_LOAD(l0 + P3_SU, bD, bX, bZ);
    P3_COMP(l0, aD, aX, aZ);
    if (l0 + 2 * P3_SU < LC) P3_LOAD(l0 + 2 * P3_SU, aD, aX, aZ);
    P3_COMP(l0 + P3_SU, bD, bX, bZ);
  }
#undef P3_LOAD
#undef P3_COMP
}

// --- RMSNorm over sum of two split-K partials; emits bf16 planes / fp32 ---
template <bool PLANES>
__global__ __launch_bounds__(256) void rmsnorm_k(const float* __restrict__ x,
                                                 const float* __restrict__ x2,
                                                 const float* __restrict__ w,
                                                 float* __restrict__ o,
                                                 unsigned short* __restrict__ op) {
  int row = blockIdx.x;
  const float* xr  = x  + (size_t)row * DIMM;
  const float* x2r = x2 + (size_t)row * DIMM;
  float s = 0.f;
  for (int i = threadIdx.x; i < DIMM; i += 256) {
    float v = xr[i] + x2r[i]; s += v * v;
  }
#pragma unroll
  for (int off = 32; off > 0; off >>= 1) s += __shfl_xor(s, off, 64);
  __shared__ float red[4];
  if ((threadIdx.x & 63) == 0) red[threadIdx.x >> 6] = s;
  __syncthreads();
  float tot = red[0] + red[1] + red[2] + red[3];
  float scale = rsqrtf(tot * (1.0f / DIMM) + 1e-5f);
  for (int i = threadIdx.x; i < DIMM; i += 256) {
    float v = (xr[i] + x2r[i]) * scale * w[i];
    if (PLANES) {
      unsigned short h1 = f2bf(v);
      op[(size_t)row * DIMM + i] = h1;
      op[(size_t)MM * DIMM + (size_t)row * DIMM + i] = f2bf(v - bf2f(h1));
    } else {
      o[(size_t)row * DIMM + i] = v;
    }
  }
}

extern "C" void kernel_launch(void* const* d_in, const int* in_sizes, int n_in,
                              void* d_out, int out_size, void* d_ws, size_t ws_size,
                              hipStream_t stream) {
  (void)in_sizes; (void)n_in; (void)out_size; (void)ws_size;
  const float* x_in    = (const float*)d_in[0];
  const float* Wi_all  = (const float*)d_in[1];
  const float* cw_all  = (const float*)d_in[2];
  const float* cb_all  = (const float*)d_in[3];
  const float* Wx_all  = (const float*)d_in[4];
  const float* Wdt_all = (const float*)d_in[5];
  const float* bdt_all = (const float*)d_in[6];
  const float* Alog_all= (const float*)d_in[7];
  const float* D_all   = (const float*)d_in[8];
  const float* Wo_all  = (const float*)d_in[9];
  const float* rw_all  = (const float*)d_in[10];
  float* out = (float*)d_out;

  float* ws    = (float*)d_ws;
  float* xz    = ws;                          // MM*2*DI  = 16777216 fl (67MB)
  float* xc    = xz   + (size_t)MM * 2 * DI;  // MM*DI    =  8388608 fl (33.5MB)
  float* xdbl  = xc   + (size_t)MM * DI;      // MM*96    =   393216 fl
  float* delta = xdbl + (size_t)MM * 96;      // MM*DI    =  8388608 fl (33.5MB)
  float* xbuf  = delta+ (size_t)MM * DI;      // MM*DIMM  =  4194304 fl (16.8MB)
  float* outtmp = xc;                         // xc lower half

  // Aliased scratch (stream-ordered; every borrow is of a provably-dead region):
  unsigned short* xpl  = (unsigned short*)delta;            // x planes (dead after in_proj)
  unsigned short* wipl = (unsigned short*)xc;               // Wi planes (dead after in_proj)
  unsigned short* wopl = (unsigned short*)(xc + (size_t)4194304); // xc upper half
  float*          Cp   = delta;                             // x_proj partials
  float* part1 = delta + (size_t)4194304;             // out_proj split-K partial (delta 2nd half)
  float* Hc   = xbuf;                                 // CHK*BD*NST = 2097152 fl
  float* Sdt  = Hc + (size_t)CHK * BD * NST;          // CHK*BD     =  131072 fl
  unsigned short* dtpl  = (unsigned short*)(xbuf + 2228224);  // 2 x MM*64 shorts (1MB)
  unsigned short* wdtpl = (unsigned short*)(xbuf + 2490368);  // 2 x DI*64 shorts (0.5MB)

  const int EW_GRID = (MM * DI) / 256;

  for (int i = 0; i < DEPTH; ++i) {
    const float* Wi   = Wi_all  + (size_t)i * (2*DI) * DIMM;
    const float* cw   = cw_all  + (size_t)i * DI * DCONVK;
    const float* cb   = cb_all  + (size_t)i * DI;
    const float* Wx   = Wx_all  + (size_t)i * 96 * DI;
    const float* Wdt  = Wdt_all + (size_t)i * DI * DTRANK;
    const float* bdt  = bdt_all + (size_t)i * DI;
    const float* Alog = Alog_all+ (size_t)i * DI * NST;
    const float* Dp   = D_all   + (size_t)i * DI;
    const float* Wo   = Wo_all  + (size_t)i * DIMM * DI;
    const float* rw   = rw_all  + (size_t)i * DIMM;

    // 1) x planes (layer 0 only; later layers get them from rmsnorm) + Wi planes
    if (i == 0)
      cvt2_k<<<(MM*DIMM)/1024, 256, 0, stream>>>(x_in, xpl, (size_t)MM * DIMM);
    cvt2_k<<<((2*DI)*DIMM)/1024, 256, 0, stream>>>(Wi, wipl, (size_t)(2*DI) * DIMM);
    // 2) in_proj: xz = x * Wi^T (256x256 3-phase pipelined MFMA)
    gemm3ph<256,1><<<dim3((2*DI)/256, MM/256, 1), 512, 0, stream>>>(
        xpl, DIMM, MM*DIMM, wipl, DIMM, (2*DI)*DIMM, xz, nullptr, 2*DI, DIMM);
    // 3) depthwise causal conv + silu -> xc
    conv_silu_k<<<EW_GRID, 256, 0, stream>>>(xz, cw, cb, xc);
    // 4) x_proj (split-K fp32); reduce also emits dt planes
    xproj_part_k<<<dim3(MM/128, 8), 256, 0, stream>>>(xc, Wx, Cp);
    xproj_red_k<<<(MM*XPN)/256, 256, 0, stream>>>(Cp, xdbl, dtpl);
    cvt2_k<<<(DI*DTRANK)/1024, 256, 0, stream>>>(Wdt, wdtpl, (size_t)DI * DTRANK);
    // 5) dt_proj (MFMA planes) + bias + softplus -> delta
    dtproj_mp<<<dim3(DI/128, MM/128), 256, 0, stream>>>(dtpl, wdtpl, bdt, delta);
    // 6) chunked selective scan (per-channel threads); pass3 emits y planes
    scan_pass1<<<dim3(BD/256, CHK), 256, 0, stream>>>(delta, xc, xdbl, Alog, Hc, Sdt);
    scan_pass2<<<(BD*NST)/256, 256, 0, stream>>>(Hc, Sdt, Alog);
    scan_pass3<<<dim3(BD/256, CHK), 256, 0, stream>>>(delta, xc, xdbl, Alog, xz, Dp, Hc);
    // 7) Wo planes into xc upper half (xc conv-data dead after pass3)
    cvt2_k<<<(DIMM*DI)/1024, 256, 0, stream>>>(Wo, wopl, (size_t)DIMM * DI);
    // 8) out_proj: 256x128 tiles, split-K=2 -> outtmp + part1 (delta dead)
    gemm3ph<128,2><<<dim3(DIMM/128, MM/256, 2), 512, 0, stream>>>(
        (const unsigned short*)xz, 8192, 2048, wopl, DI, DIMM*DI,
        outtmp, part1, DIMM, DI);
    // 9) rmsnorm over (outtmp+part1) -> x planes (fp32 to d_out on last layer)
    if (i < DEPTH - 1)
      rmsnorm_k<true><<<MM, 256, 0, stream>>>(outtmp, part1, rw, nullptr, xpl);
    else
      rmsnorm_k<false><<<MM, 256, 0, stream>>>(outtmp, part1, rw, out, nullptr);
  }
}

// Round 6
// 2936.418 us; speedup vs baseline: 1.1027x; 1.1027x over previous
//
#include <hip/hip_runtime.h>
#include <cstddef>

// Problem constants (fixed by the reference)
#define DEPTH  8
#define DIMM   1024
#define DI     2048      // d_inner
#define NST    16        // d_state
#define DCONVK 4
#define DTRANK 64
#define BB     2
#define LL     2048
#define MM     (BB*LL)   // 4096 rows
#define BD     (BB*DI)   // 4096 channels
#define CHK    64        // scan chunks (R6: 32->64 for 4 blk/CU occupancy)
#define LC     (LL/CHK)  // 32 timesteps per chunk
#define LOG2E  1.44269504088896f

typedef __attribute__((ext_vector_type(8))) short bf16x8;
typedef __attribute__((ext_vector_type(4))) float f32x4;

__device__ __forceinline__ float fexp2(float x) {
  // raw v_exp_f32; identical to ocml exp2f for x >= -126 (our dt*Av <= 0
  // args only differ where results are ~1e-38 denormals -> flushed)
  return __builtin_amdgcn_exp2f(x);
}

// ================= fp32 -> bf16 plane split helpers =================
__device__ __forceinline__ unsigned short f2bf(float f) {
  unsigned int u = __float_as_uint(f);
  unsigned int r = (u + 0x7fffu + ((u >> 16) & 1u)) >> 16;   // RNE
  return (unsigned short)r;
}
__device__ __forceinline__ float bf2f(unsigned short h) {
  return __uint_as_float(((unsigned int)h) << 16);
}

// x[n] fp32 -> 2 planes (hi, lo) at p[0..n), p[n..2n)
__global__ __launch_bounds__(256) void cvt2_k(const float* __restrict__ x,
                                              unsigned short* __restrict__ p,
                                              size_t n) {
  size_t i = ((size_t)blockIdx.x * 256 + threadIdx.x) * 4;
  float4 v = *(const float4*)(x + i);
  float vv[4] = {v.x, v.y, v.z, v.w};
  unsigned short u1[4], u2[4];
#pragma unroll
  for (int k = 0; k < 4; ++k) {
    unsigned short h1 = f2bf(vv[k]);
    u1[k] = h1;
    u2[k] = f2bf(vv[k] - bf2f(h1));
  }
  *(ushort4*)(p + i)     = make_ushort4(u1[0], u1[1], u1[2], u1[3]);
  *(ushort4*)(p + n + i) = make_ushort4(u2[0], u2[1], u2[2], u2[3]);
}

// ===== 3-phase pipelined 3-product 2-plane bf16 MFMA GEMM: C = A*B^T =====
// BM=256; BN in {256,128}; optional split-K=2 (z-dim, separate outputs).
// Per K32-tile: ph0 = A0*B0, ph1 = A0*B1, ph2 = A1*B0; every vmcnt wait has
// >=2 phases of prefetch cover (2-phase merge regressed: 1-phase cover).
template <int BN, int NSPLIT>
__global__ __launch_bounds__(512, 2) void gemm3ph(
    const unsigned short* __restrict__ Ap, int lda_a, int pstr_a,
    const unsigned short* __restrict__ Bp, int lda_b, int pstr_b,
    float* __restrict__ C0, float* __restrict__ C1, int N, int Ktot) {
  constexpr int BM  = 256;
  constexpr int BF  = BN / 64;          // per-wave N-fragments (4 or 2)
  constexpr int BL  = BN / 128;         // B issues per plane (2 or 1)
  constexpr int RA1 = BM * 32;          // region offsets in shorts
  constexpr int RB0 = 2 * BM * 32;
  constexpr int RB1 = RB0 + BN * 32;
  constexpr int BUFS = (2 * BM + 2 * BN) * 32;   // shorts per buffer
  __shared__ unsigned short S[2 * BUFS];

  const int t  = threadIdx.x;
  const int w  = t >> 6;
  const int l  = t & 63;
  const int lm = l & 15;
  const int qs = ((l >> 4) << 3) ^ (((lm >> 1) & 3) << 3);

  // T1: XCD-aware bijective block swizzle (nwg % 8 == 0 in both uses)
  const int nx   = gridDim.x;
  const int nwg  = nx * gridDim.y;
  const int flat = blockIdx.y * nx + blockIdx.x;
  const int swz  = (flat & 7) * (nwg >> 3) + (flat >> 3);
  const int m0 = (swz / nx) * BM;
  const int n0 = (swz % nx) * BN;
  const int z  = (NSPLIT == 2) ? blockIdx.z : 0;
  const int KS = Ktot / NSPLIT;

  const int wm = (w & 1) << 7;          // 0 / 128
  const int wn = (w >> 1) * (BN / 4);   // 4 N-waves

  const int rr = t >> 2;
  const int kq = ((t & 3) ^ ((rr >> 1) & 3)) << 3;
  const unsigned short* srcA = Ap + (size_t)(m0 + rr) * lda_a + (size_t)z * KS + kq;
  const unsigned short* srcB = Bp + (size_t)(n0 + rr) * lda_b + (size_t)z * KS + kq;
  const size_t a128 = (size_t)128 * lda_a;
  const size_t b128 = (size_t)128 * lda_b;
  const int dbase = (w << 6) * 8;       // wave-uniform dst base (shorts)

#define GI(p_, off_)                                                           \
  __builtin_amdgcn_global_load_lds(                                            \
      (const __attribute__((address_space(1))) unsigned int*)(p_),             \
      (__attribute__((address_space(3))) unsigned int*)&S[bnext + (off_) + dbase], \
      16, 0, 0)

#define GI_PH0(kb_)                                                            \
  { GI(srcA + (kb_), 0); GI(srcA + a128 + (kb_), 4096);                        \
    GI(srcB + (kb_), RB0);                                                     \
    if constexpr (BL == 2) GI(srcB + b128 + (kb_), RB0 + 4096); }

#define GI_PH1(kb_)                                                            \
  { GI(srcB + (size_t)pstr_b + (kb_), RB1);                                    \
    if constexpr (BL == 2) GI(srcB + (size_t)pstr_b + b128 + (kb_), RB1 + 4096); }

#define GI_PH2(kb_)                                                            \
  { GI(srcA + (size_t)pstr_a + (kb_), RA1);                                    \
    GI(srcA + (size_t)pstr_a + a128 + (kb_), RA1 + 4096); }

  f32x4 acc[8][BF];
#pragma unroll
  for (int i = 0; i < 8; ++i)
#pragma unroll
    for (int j = 0; j < BF; ++j) acc[i][j] = (f32x4){0.f, 0.f, 0.f, 0.f};

  { // prologue: stage tile 0 into buf0; queue order A0,B0 | B1 | A1
    const int bnext = 0;
    GI_PH0((size_t)0);
    GI_PH1((size_t)0);
    GI_PH2((size_t)0);
  }
  if constexpr (BN == 256) asm volatile("s_waitcnt vmcnt(4)" ::: "memory");
  else                     asm volatile("s_waitcnt vmcnt(3)" ::: "memory");
  __builtin_amdgcn_s_barrier();

  const int NT = KS >> 5;
#pragma unroll 2
  for (int ti = 0; ti < NT; ++ti) {
    const int bcur  = (ti & 1) ? BUFS : 0;
    const int bnext = (ti & 1) ? 0 : BUFS;
    const size_t kb = (size_t)((ti + 1 < NT) ? (ti + 1) : 0) * 32; // dummy tail prefetch
    const unsigned short* Sb = &S[bcur];
    bf16x8 a[8], b0[BF], b1[BF];

    // ---- phase 0: A0 x B0 ----
#pragma unroll
    for (int i = 0; i < 8; ++i)
      a[i] = *(const bf16x8*)&Sb[(wm + i * 16 + lm) * 32 + qs];
#pragma unroll
    for (int j = 0; j < BF; ++j)
      b0[j] = *(const bf16x8*)&Sb[RB0 + (wn + j * 16 + lm) * 32 + qs];
    GI_PH0(kb);
    if constexpr (BN == 256) asm volatile("s_waitcnt vmcnt(6)" ::: "memory");
    else                     asm volatile("s_waitcnt vmcnt(5)" ::: "memory");
    __builtin_amdgcn_s_barrier();
    asm volatile("s_waitcnt lgkmcnt(0)" ::: "memory");
    __builtin_amdgcn_s_setprio(1);
#pragma unroll
    for (int i = 0; i < 8; ++i)
#pragma unroll
      for (int j = 0; j < BF; ++j)
        acc[i][j] = __builtin_amdgcn_mfma_f32_16x16x32_bf16(a[i], b0[j], acc[i][j], 0, 0, 0);
    __builtin_amdgcn_s_setprio(0);
    __builtin_amdgcn_s_barrier();

    // ---- phase 1: A0 x B1 ----
#pragma unroll
    for (int j = 0; j < BF; ++j)
      b1[j] = *(const bf16x8*)&Sb[RB1 + (wn + j * 16 + lm) * 32 + qs];
    GI_PH1(kb);
    if constexpr (BN == 256) asm volatile("s_waitcnt vmcnt(6)" ::: "memory");
    else                     asm volatile("s_waitcnt vmcnt(4)" ::: "memory");
    __builtin_amdgcn_s_barrier();
    asm volatile("s_waitcnt lgkmcnt(0)" ::: "memory");
    __builtin_amdgcn_s_setprio(1);
#pragma unroll
    for (int i = 0; i < 8; ++i)
#pragma unroll
      for (int j = 0; j < BF; ++j)
        acc[i][j] = __builtin_amdgcn_mfma_f32_16x16x32_bf16(a[i], b1[j], acc[i][j], 0, 0, 0);
    __builtin_amdgcn_s_setprio(0);
    __builtin_amdgcn_s_barrier();

    // ---- phase 2: A1 x B0 ----
#pragma unroll
    for (int i = 0; i < 8; ++i)
      a[i] = *(const bf16x8*)&Sb[RA1 + (wm + i * 16 + lm) * 32 + qs];
    GI_PH2(kb);
    if constexpr (BN == 256) asm volatile("s_waitcnt vmcnt(4)" ::: "memory");
    else                     asm volatile("s_waitcnt vmcnt(3)" ::: "memory");
    __builtin_amdgcn_s_barrier();
    asm volatile("s_waitcnt lgkmcnt(0)" ::: "memory");
    __builtin_amdgcn_s_setprio(1);
#pragma unroll
    for (int i = 0; i < 8; ++i)
#pragma unroll
      for (int j = 0; j < BF; ++j)
        acc[i][j] = __builtin_amdgcn_mfma_f32_16x16x32_bf16(a[i], b0[j], acc[i][j], 0, 0, 0);
    __builtin_amdgcn_s_setprio(0);
    __builtin_amdgcn_s_barrier();
  }
#undef GI_PH2
#undef GI_PH1
#undef GI_PH0
#undef GI

  float* Cc = (NSPLIT == 2 && blockIdx.z) ? C1 : C0;
  const int row0 = (l >> 4) << 2;
#pragma unroll
  for (int i = 0; i < 8; ++i)
#pragma unroll
    for (int j = 0; j < BF; ++j)
#pragma unroll
      for (int r = 0; r < 4; ++r) {
        int m = m0 + wm + i * 16 + row0 + r;
        int n = n0 + wn + j * 16 + lm;
        Cc[(size_t)m * N + n] = acc[i][j][r];
      }
}

// ------- dt_proj via MFMA planes, fused bias+softplus -------
__global__ __launch_bounds__(256) void dtproj_mp(const unsigned short* __restrict__ Ap,
                                                 const unsigned short* __restrict__ Bp,
                                                 const float* __restrict__ bdt,
                                                 float* __restrict__ Cd) {
  __shared__ unsigned short S[32768];   // 2 ktiles x (2 planes A + 2 planes B) x 128 x 32
  const int t  = threadIdx.x;
  const int w  = t >> 6;
  const int l  = t & 63;
  const int lm = l & 15;
  const int q8 = (l >> 4) << 3;
  const int qs = q8 ^ (((lm >> 1) & 3) << 3);
  const int m0 = blockIdx.y * 128;
  const int n0 = blockIdx.x * 128;
  const int wm = (w & 1) << 6;
  const int wn = (w >> 1) << 6;

#pragma unroll
  for (int it = 0; it < 16; ++it) {
    int c  = it * 256 + t;
    int kt = c >> 11;
    int c2 = c & 2047;
    const unsigned short* base;
    int r, aslot;
    if (c2 < 1024) {
      int p = c2 >> 9; int wi = c2 & 511; r = wi >> 2; aslot = wi & 3;
      base = Ap + (size_t)p * (MM * 64) + (size_t)(m0 + r) * 64;
    } else {
      int c3 = c2 - 1024;
      int p = c3 >> 9; int wi = c3 & 511; r = wi >> 2; aslot = wi & 3;
      base = Bp + (size_t)p * (DI * 64) + (size_t)(n0 + r) * 64;
    }
    int kq = (aslot ^ ((r >> 1) & 3)) << 3;
    __builtin_amdgcn_global_load_lds(
        (const __attribute__((address_space(1))) unsigned int*)(base + kt * 32 + kq),
        (__attribute__((address_space(3))) unsigned int*)&S[(size_t)(it * 256 + (w << 6)) * 8],
        16, 0, 0);
  }
  __syncthreads();

  f32x4 acc[4][4];
#pragma unroll
  for (int i = 0; i < 4; ++i)
#pragma unroll
    for (int j = 0; j < 4; ++j) acc[i][j] = (f32x4){0.f, 0.f, 0.f, 0.f};

#pragma unroll
  for (int kt = 0; kt < 2; ++kt) {
    const int RA = kt * 16384;          // A plane0 region (shorts)
    const int RB = kt * 16384 + 8192;   // B plane0 region
    bf16x8 a0[4], aX[4], b0[4];
#pragma unroll
    for (int i = 0; i < 4; ++i)
      a0[i] = *(const bf16x8*)&S[RA + (wm + i * 16 + lm) * 32 + qs];
#pragma unroll
    for (int j = 0; j < 4; ++j)
      b0[j] = *(const bf16x8*)&S[RB + (wn + j * 16 + lm) * 32 + qs];
#pragma unroll
    for (int i = 0; i < 4; ++i)
#pragma unroll
      for (int j = 0; j < 4; ++j)
        acc[i][j] = __builtin_amdgcn_mfma_f32_16x16x32_bf16(a0[i], b0[j], acc[i][j], 0, 0, 0);
#pragma unroll
    for (int j = 0; j < 4; ++j)        // B plane 1
      aX[j] = *(const bf16x8*)&S[RB + 4096 + (wn + j * 16 + lm) * 32 + qs];
#pragma unroll
    for (int i = 0; i < 4; ++i)
#pragma unroll
      for (int j = 0; j < 4; ++j)
        acc[i][j] = __builtin_amdgcn_mfma_f32_16x16x32_bf16(a0[i], aX[j], acc[i][j], 0, 0, 0);
#pragma unroll
    for (int i = 0; i < 4; ++i)        // A plane 1
      aX[i] = *(const bf16x8*)&S[RA + 4096 + (wm + i * 16 + lm) * 32 + qs];
#pragma unroll
    for (int i = 0; i < 4; ++i)
#pragma unroll
      for (int j = 0; j < 4; ++j)
        acc[i][j] = __builtin_amdgcn_mfma_f32_16x16x32_bf16(aX[i], b0[j], acc[i][j], 0, 0, 0);
  }

  const int row0 = (l >> 4) << 2;
#pragma unroll
  for (int j = 0; j < 4; ++j) {
    int n = n0 + wn + j * 16 + lm;
    float bv = bdt[n];
#pragma unroll
    for (int i = 0; i < 4; ++i)
#pragma unroll
      for (int r = 0; r < 4; ++r) {
        int m = m0 + wm + i * 16 + row0 + r;
        float x = acc[i][j][r] + bv;
        Cd[(size_t)m * DI + n] = fmaxf(x, 0.f) + log1pf(expf(-fabsf(x)));
      }
  }
}

// ---------------- x_proj split-K: C[4096,96] = xc * Wx^T ----------------
#define XPN 96
__global__ __launch_bounds__(256) void xproj_part_k(const float* __restrict__ A,
                                                    const float* __restrict__ W,
                                                    float* __restrict__ Cp) {
  __shared__ float As[16][128];
  __shared__ float Ws[16][XPN];
  const int t  = threadIdx.x;
  const int tx = t & 15;
  const int ty = t >> 4;
  const int m0 = blockIdx.x * 128;
  const int kb = blockIdx.y * 256;
  float acc[8][6];
#pragma unroll
  for (int i = 0; i < 8; ++i)
#pragma unroll
    for (int j = 0; j < 6; ++j) acc[i][j] = 0.f;

  for (int k0 = kb; k0 < kb + 256; k0 += 16) {
#pragma unroll
    for (int e = t; e < 512; e += 256) {
      int r = e >> 2, cq = (e & 3) << 2;
      float4 v = *(const float4*)(A + (size_t)(m0 + r) * DI + k0 + cq);
      As[cq+0][r] = v.x; As[cq+1][r] = v.y; As[cq+2][r] = v.z; As[cq+3][r] = v.w;
    }
    for (int e = t; e < 384; e += 256) {
      int r = e >> 2, cq = (e & 3) << 2;
      float4 v = *(const float4*)(W + (size_t)r * DI + k0 + cq);
      Ws[cq+0][r] = v.x; Ws[cq+1][r] = v.y; Ws[cq+2][r] = v.z; Ws[cq+3][r] = v.w;
    }
    __syncthreads();
#pragma unroll
    for (int kk = 0; kk < 16; ++kk) {
      float a[8], b[6];
#pragma unroll
      for (int i = 0; i < 8; ++i) a[i] = As[kk][ty*8 + i];
#pragma unroll
      for (int j = 0; j < 6; ++j) b[j] = Ws[kk][tx*6 + j];
#pragma unroll
      for (int i = 0; i < 8; ++i)
#pragma unroll
        for (int j = 0; j < 6; ++j) acc[i][j] += a[i] * b[j];
    }
    __syncthreads();
  }
  float* cp = Cp + (size_t)blockIdx.y * MM * XPN;
#pragma unroll
  for (int i = 0; i < 8; ++i)
#pragma unroll
    for (int j = 0; j < 6; ++j)
      cp[(size_t)(m0 + ty*8 + i) * XPN + tx*6 + j] = acc[i][j];
}

// reduce partials -> fp32 xdbl; dt columns (0..63) also emitted as 2 bf16 planes
__global__ __launch_bounds__(256) void xproj_red_k(const float* __restrict__ Cp,
                                                   float* __restrict__ o,
                                                   unsigned short* __restrict__ dtp) {
  int i = blockIdx.x * 256 + threadIdx.x;    // MM*96
  float s = 0.f;
#pragma unroll
  for (int ks = 0; ks < 8; ++ks) s += Cp[(size_t)ks * (MM * XPN) + i];
  o[i] = s;
  int m = i / 96, col = i - m * 96;
  if (col < DTRANK) {
    unsigned short h1 = f2bf(s);
    dtp[(size_t)m * DTRANK + col] = h1;
    dtp[(size_t)MM * DTRANK + (size_t)m * DTRANK + col] = f2bf(s - bf2f(h1));
  }
}

__device__ __forceinline__ float fast_silu(float x) {
  return x * __builtin_amdgcn_rcpf(1.f + fexp2(-LOG2E * x));
}

// ---------------- depthwise causal conv1d + SiLU ----------------
__global__ __launch_bounds__(256) void conv_silu_k(const float* __restrict__ xz,
                                                   const float* __restrict__ cw,
                                                   const float* __restrict__ cb,
                                                   float* __restrict__ xc) {
  int idx = blockIdx.x * 256 + threadIdx.x;
  int c  = idx & (DI - 1);
  int bl = idx >> 11;
  int l  = bl & (LL - 1);
  float acc = cb[c];
#pragma unroll
  for (int k = 0; k < DCONVK; ++k) {
    int ls = l - (DCONVK - 1) + k;
    if (ls >= 0)
      acc += xz[(size_t)(bl - (DCONVK - 1) + k) * (2*DI) + c] * cw[c*DCONVK + k];
  }
  xc[idx] = fast_silu(acc);
}

// ======================= chunked selective scan =======================
// Per-channel threads (1 thread = 1 channel x 1 chunk, 16 states in regs).
// R6: CHK=64 (LC=32) -> grid 1024 blocks = 4 blk/CU (R5's 512 blocks = 2
// blk/CU starved latency hiding and masked the lean-mapping win); raw
// v_exp_f32; deeper pass3 prefetch (SU=4).
__global__ __launch_bounds__(256) void scan_pass1(const float* __restrict__ delta,
                                                  const float* __restrict__ xc,
                                                  const float* __restrict__ xdbl,
                                                  const float* __restrict__ A_log,
                                                  float* __restrict__ Hc,
                                                  float* __restrict__ Sdt) {
  const int t  = threadIdx.x;
  const int g  = blockIdx.x;          // 16 channel groups of 256
  const int c  = blockIdx.y;          // CHK chunks
  const int ch = g * 256 + t;
  const int b  = ch >> 11;            // block-uniform
  const int d  = ch & (DI - 1);
  const size_t rowbase = (size_t)b * LL + (size_t)c * LC;

  __shared__ float Bs[LC * 16];   // 2KB: B rows of this chunk
  if (t < LC * 4) {
    int row = t >> 2, seg = t & 3;
    *(float4*)&Bs[row * 16 + seg * 4] =
        *(const float4*)(xdbl + (rowbase + row) * 96 + DTRANK + seg * 4);
  }
  __syncthreads();

  float Av[NST];
#pragma unroll
  for (int n4 = 0; n4 < 4; ++n4) {
    float4 al = *(const float4*)(A_log + (size_t)d * NST + n4 * 4);
    Av[n4*4+0] = -expf(al.x) * LOG2E;
    Av[n4*4+1] = -expf(al.y) * LOG2E;
    Av[n4*4+2] = -expf(al.z) * LOG2E;
    Av[n4*4+3] = -expf(al.w) * LOG2E;
  }
  float h[NST];
#pragma unroll
  for (int n = 0; n < NST; ++n) h[n] = 0.f;
  float S = 0.f;

#define P1_SU 4
  float aD[P1_SU], aX[P1_SU];
  float bD[P1_SU], bX[P1_SU];

#define P1_LOAD(l0, D_, X_)                                            \
  { _Pragma("unroll")                                                  \
    for (int u = 0; u < P1_SU; ++u) {                                  \
      size_t bl = rowbase + (l0) + u;                                  \
      D_[u] = delta[bl * DI + d];                                      \
      X_[u] = xc[bl * DI + d];                                         \
    } }

#define P1_COMP(l0, D_, X_)                                            \
  { _Pragma("unroll")                                                  \
    for (int u = 0; u < P1_SU; ++u) {                                  \
      float dt = D_[u], uB = dt * X_[u];                               \
      const f32x4* B4 = (const f32x4*)&Bs[((l0) + u) * 16];            \
      f32x4 B0 = B4[0], B1 = B4[1], B2 = B4[2], B3 = B4[3];            \
      _Pragma("unroll")                                                \
      for (int n = 0; n < 4; ++n) {                                    \
        h[n]      = fmaf(fexp2(dt * Av[n]),      h[n],      uB * B0[n]); \
        h[4 + n]  = fmaf(fexp2(dt * Av[4 + n]),  h[4 + n],  uB * B1[n]); \
        h[8 + n]  = fmaf(fexp2(dt * Av[8 + n]),  h[8 + n],  uB * B2[n]); \
        h[12 + n] = fmaf(fexp2(dt * Av[12 + n]), h[12 + n], uB * B3[n]); \
      }                                                                \
      S += dt;                                                         \
    } }

  P1_LOAD(0, aD, aX);
  for (int l0 = 0; l0 < LC; l0 += 2 * P1_SU) {
    P1_LOAD(l0 + P1_SU, bD, bX);
    P1_COMP(l0, aD, aX);
    if (l0 + 2 * P1_SU < LC) P1_LOAD(l0 + 2 * P1_SU, aD, aX);
    P1_COMP(l0 + P1_SU, bD, bX);
  }
#undef P1_LOAD
#undef P1_COMP

  float* hp = Hc + ((size_t)c * BD + ch) * NST;
#pragma unroll
  for (int n4 = 0; n4 < 4; ++n4)
    *(float4*)(hp + n4 * 4) =
        make_float4(h[n4*4], h[n4*4+1], h[n4*4+2], h[n4*4+3]);
  Sdt[(size_t)c * BD + ch] = S;
}

__global__ __launch_bounds__(256) void scan_pass2(float* __restrict__ Hc,
                                                  const float* __restrict__ Sdt,
                                                  const float* __restrict__ A_log) {
  const int g  = blockIdx.x * 256 + threadIdx.x;
  const int n  = g & (NST - 1);
  const int ch = g >> 4;
  const int d  = ch & (DI - 1);
  const float Av2 = -expf(A_log[d * NST + n]) * LOG2E;
  float Sv[CHK];
#pragma unroll
  for (int c = 0; c < CHK; ++c) Sv[c] = Sdt[(size_t)c * BD + ch];
  float h = 0.f;
  float tmp = Hc[(size_t)ch * NST + n];
#pragma unroll
  for (int c = 0; c < CHK; ++c) {
    size_t idx = ((size_t)c * BD + ch) * NST + n;
    float tnext = (c + 1 < CHK) ? Hc[((size_t)(c+1) * BD + ch) * NST + n] : 0.f;
    Hc[idx] = h;
    h = fmaf(fexp2(Av2 * Sv[c]), h, tmp);
    tmp = tnext;
  }
}

// pass3: re-scan from true start state, per-channel threads; emits gated y
// as 2 bf16 planes via coalesced all-lane ushort stores into xz's xs-half.
__global__ __launch_bounds__(256) void scan_pass3(const float* __restrict__ delta,
                                                  const float* __restrict__ xc,
                                                  const float* __restrict__ xdbl,
                                                  const float* __restrict__ A_log,
                                                  float* __restrict__ xzp,
                                                  const float* __restrict__ Dp,
                                                  const float* __restrict__ Hc) {
  const int t  = threadIdx.x;
  const int g  = blockIdx.x;
  const int c  = blockIdx.y;
  const int ch = g * 256 + t;
  const int b  = ch >> 11;
  const int d  = ch & (DI - 1);
  const size_t rowbase = (size_t)b * LL + (size_t)c * LC;

  __shared__ float BCs[LC * 32];  // 4KB: B|C rows of this chunk
  { int row = t >> 3, seg = t & 7;
    *(float4*)&BCs[row * 32 + seg * 4] =
        *(const float4*)(xdbl + (rowbase + row) * 96 + DTRANK + seg * 4);
  }
  __syncthreads();

  float Av[NST];
#pragma unroll
  for (int n4 = 0; n4 < 4; ++n4) {
    float4 al = *(const float4*)(A_log + (size_t)d * NST + n4 * 4);
    Av[n4*4+0] = -expf(al.x) * LOG2E;
    Av[n4*4+1] = -expf(al.y) * LOG2E;
    Av[n4*4+2] = -expf(al.z) * LOG2E;
    Av[n4*4+3] = -expf(al.w) * LOG2E;
  }
  const float Dv = Dp[d];
  float h[NST];
  { const float* hp = Hc + ((size_t)c * BD + ch) * NST;
#pragma unroll
    for (int n4 = 0; n4 < 4; ++n4) {
      float4 hv = *(const float4*)(hp + n4 * 4);
      h[n4*4+0] = hv.x; h[n4*4+1] = hv.y; h[n4*4+2] = hv.z; h[n4*4+3] = hv.w;
    }
  }
  unsigned short* yp = (unsigned short*)xzp;

#define P3_SU 4
  float aD[P3_SU], aX[P3_SU], aZ[P3_SU];
  float bD[P3_SU], bX[P3_SU], bZ[P3_SU];

#define P3_LOAD(l0, D_, X_, Z_)                                        \
  { _Pragma("unroll")                                                  \
    for (int u = 0; u < P3_SU; ++u) {                                  \
      size_t bl = rowbase + (l0) + u;                                  \
      D_[u] = delta[bl * DI + d];                                      \
      X_[u] = xc[bl * DI + d];                                         \
      Z_[u] = xzp[bl * (2*DI) + DI + d];                               \
    } }

#define P3_COMP(l0, D_, X_, Z_)                                        \
  { _Pragma("unroll")                                                  \
    for (int u = 0; u < P3_SU; ++u) {                                  \
      float dt = D_[u], uB = dt * X_[u];                               \
      const f32x4* R4 = (const f32x4*)&BCs[((l0) + u) * 32];           \
      f32x4 B0 = R4[0], B1 = R4[1], B2 = R4[2], B3 = R4[3];            \
      f32x4 C0 = R4[4], C1 = R4[5], C2 = R4[6], C3 = R4[7];            \
      _Pragma("unroll")                                                \
      for (int n = 0; n < 4; ++n) {                                    \
        h[n]      = fmaf(fexp2(dt * Av[n]),      h[n],      uB * B0[n]); \
        h[4 + n]  = fmaf(fexp2(dt * Av[4 + n]),  h[4 + n],  uB * B1[n]); \
        h[8 + n]  = fmaf(fexp2(dt * Av[8 + n]),  h[8 + n],  uB * B2[n]); \
        h[12 + n] = fmaf(fexp2(dt * Av[12 + n]), h[12 + n], uB * B3[n]); \
      }                                                                \
      /* same fma tree as the original shuffle reduction */            \
      float p0 = fmaf(h[1],  C0[1], h[0]  * C0[0]);                    \
      p0 += fmaf(h[3],  C0[3], h[2]  * C0[2]);                         \
      float p1 = fmaf(h[5],  C1[1], h[4]  * C1[0]);                    \
      p1 += fmaf(h[7],  C1[3], h[6]  * C1[2]);                         \
      float p2 = fmaf(h[9],  C2[1], h[8]  * C2[0]);                    \
      p2 += fmaf(h[11], C2[3], h[10] * C2[2]);                         \
      float p3 = fmaf(h[13], C3[1], h[12] * C3[0]);                    \
      p3 += fmaf(h[15], C3[3], h[14] * C3[2]);                         \
      float s = (p0 + p1) + (p2 + p3);                                 \
      float yv = (s + X_[u] * Dv) * fast_silu(Z_[u]);                  \
      unsigned short y1 = f2bf(yv);                                    \
      size_t yb = (rowbase + (l0) + u) * 8192 + d;                     \
      yp[yb] = y1;                                                     \
      yp[yb + 2048] = f2bf(yv - bf2f(y1));                             \
    } }

  P3_LOAD(0, aD, aX, aZ);
  for (int l0 = 0; l0 < LC; l0 += 2 * P3_SU) {
    P3_LOAD(l0 + P3_SU, bD, bX, bZ);
    P3_COMP(l0, aD, aX, aZ);
    if (l0 + 2 * P3_SU < LC) P3_LOAD(l0 + 2 * P3_SU, aD, aX, aZ);
    P3_COMP(l0 + P3_SU, bD, bX, bZ);
  }
#undef P3_LOAD
#undef P3_COMP
}

// --- RMSNorm over sum of two split-K partials; emits bf16 planes / fp32 ---
template <bool PLANES>
__global__ __launch_bounds__(256) void rmsnorm_k(const float* __restrict__ x,
                                                 const float* __restrict__ x2,
                                                 const float* __restrict__ w,
                                                 float* __restrict__ o,
                                                 unsigned short* __restrict__ op) {
  int row = blockIdx.x;
  const float* xr  = x  + (size_t)row * DIMM;
  const float* x2r = x2 + (size_t)row * DIMM;
  float s = 0.f;
  for (int i = threadIdx.x; i < DIMM; i += 256) {
    float v = xr[i] + x2r[i]; s += v * v;
  }
#pragma unroll
  for (int off = 32; off > 0; off >>= 1) s += __shfl_xor(s, off, 64);
  __shared__ float red[4];
  if ((threadIdx.x & 63) == 0) red[threadIdx.x >> 6] = s;
  __syncthreads();
  float tot = red[0] + red[1] + red[2] + red[3];
  float scale = rsqrtf(tot * (1.0f / DIMM) + 1e-5f);
  for (int i = threadIdx.x; i < DIMM; i += 256) {
    float v = (xr[i] + x2r[i]) * scale * w[i];
    if (PLANES) {
      unsigned short h1 = f2bf(v);
      op[(size_t)row * DIMM + i] = h1;
      op[(size_t)MM * DIMM + (size_t)row * DIMM + i] = f2bf(v - bf2f(h1));
    } else {
      o[(size_t)row * DIMM + i] = v;
    }
  }
}

extern "C" void kernel_launch(void* const* d_in, const int* in_sizes, int n_in,
                              void* d_out, int out_size, void* d_ws, size_t ws_size,
                              hipStream_t stream) {
  (void)in_sizes; (void)n_in; (void)out_size; (void)ws_size;
  const float* x_in    = (const float*)d_in[0];
  const float* Wi_all  = (const float*)d_in[1];
  const float* cw_all  = (const float*)d_in[2];
  const float* cb_all  = (const float*)d_in[3];
  const float* Wx_all  = (const float*)d_in[4];
  const float* Wdt_all = (const float*)d_in[5];
  const float* bdt_all = (const float*)d_in[6];
  const float* Alog_all= (const float*)d_in[7];
  const float* D_all   = (const float*)d_in[8];
  const float* Wo_all  = (const float*)d_in[9];
  const float* rw_all  = (const float*)d_in[10];
  float* out = (float*)d_out;

  float* ws    = (float*)d_ws;
  float* xz    = ws;                          // MM*2*DI  = 16777216 fl (67MB)
  float* xc    = xz   + (size_t)MM * 2 * DI;  // MM*DI    =  8388608 fl (33.5MB)
  float* xdbl  = xc   + (size_t)MM * DI;      // MM*96    =   393216 fl
  float* delta = xdbl + (size_t)MM * 96;      // MM*DI    =  8388608 fl (33.5MB)
  float* xbuf  = delta+ (size_t)MM * DI;      // MM*DIMM  =  4194304 fl (16.8MB)
  float* outtmp = xc;                         // xc lower half

  // Aliased scratch (stream-ordered; every borrow is of a provably-dead region):
  unsigned short* xpl  = (unsigned short*)delta;            // x planes (dead after in_proj)
  unsigned short* wipl = (unsigned short*)xc;               // Wi planes (dead after in_proj)
  unsigned short* wopl = (unsigned short*)(xc + (size_t)4194304); // xc upper half
  float*          Cp   = delta;                             // x_proj partials
  float* part1 = delta + (size_t)4194304;             // out_proj split-K partial (delta 2nd half)
  // R6: CHK=64 -> Hc = CHK*BD*NST = 4194304 fl = ALL of xbuf. Sdt/dtpl/wdtpl
  // live in d_out as scratch (all scratch reads complete before the final
  // rmsnorm overwrites d_out; stream-ordered, fully rewritten each layer).
  float* Hc   = xbuf;                                 // CHK*BD*NST = 4194304 fl
  unsigned short* dtpl  = (unsigned short*)out;             // 2 x MM*64 shorts (1MB)
  unsigned short* wdtpl = (unsigned short*)(out + 262144);  // 2 x DI*64 shorts (0.5MB)
  float* Sdt  = out + 393216;                         // CHK*BD = 262144 fl (1MB)

  const int EW_GRID = (MM * DI) / 256;

  for (int i = 0; i < DEPTH; ++i) {
    const float* Wi   = Wi_all  + (size_t)i * (2*DI) * DIMM;
    const float* cw   = cw_all  + (size_t)i * DI * DCONVK;
    const float* cb   = cb_all  + (size_t)i * DI;
    const float* Wx   = Wx_all  + (size_t)i * 96 * DI;
    const float* Wdt  = Wdt_all + (size_t)i * DI * DTRANK;
    const float* bdt  = bdt_all + (size_t)i * DI;
    const float* Alog = Alog_all+ (size_t)i * DI * NST;
    const float* Dp   = D_all   + (size_t)i * DI;
    const float* Wo   = Wo_all  + (size_t)i * DIMM * DI;
    const float* rw   = rw_all  + (size_t)i * DIMM;

    // 1) x planes (layer 0 only; later layers get them from rmsnorm) + Wi planes
    if (i == 0)
      cvt2_k<<<(MM*DIMM)/1024, 256, 0, stream>>>(x_in, xpl, (size_t)MM * DIMM);
    cvt2_k<<<((2*DI)*DIMM)/1024, 256, 0, stream>>>(Wi, wipl, (size_t)(2*DI) * DIMM);
    // 2) in_proj: xz = x * Wi^T (256x256 3-phase pipelined MFMA)
    gemm3ph<256,1><<<dim3((2*DI)/256, MM/256, 1), 512, 0, stream>>>(
        xpl, DIMM, MM*DIMM, wipl, DIMM, (2*DI)*DIMM, xz, nullptr, 2*DI, DIMM);
    // 3) depthwise causal conv + silu -> xc
    conv_silu_k<<<EW_GRID, 256, 0, stream>>>(xz, cw, cb, xc);
    // 4) x_proj (split-K fp32); reduce also emits dt planes
    xproj_part_k<<<dim3(MM/128, 8), 256, 0, stream>>>(xc, Wx, Cp);
    xproj_red_k<<<(MM*XPN)/256, 256, 0, stream>>>(Cp, xdbl, dtpl);
    cvt2_k<<<(DI*DTRANK)/1024, 256, 0, stream>>>(Wdt, wdtpl, (size_t)DI * DTRANK);
    // 5) dt_proj (MFMA planes) + bias + softplus -> delta
    dtproj_mp<<<dim3(DI/128, MM/128), 256, 0, stream>>>(dtpl, wdtpl, bdt, delta);
    // 6) chunked selective scan (per-channel threads, CHK=64 -> 1024 blocks)
    scan_pass1<<<dim3(BD/256, CHK), 256, 0, stream>>>(delta, xc, xdbl, Alog, Hc, Sdt);
    scan_pass2<<<(BD*NST)/256, 256, 0, stream>>>(Hc, Sdt, Alog);
    scan_pass3<<<dim3(BD/256, CHK), 256, 0, stream>>>(delta, xc, xdbl, Alog, xz, Dp, Hc);
    // 7) Wo planes into xc upper half (xc conv-data dead after pass3)
    cvt2_k<<<(DIMM*DI)/1024, 256, 0, stream>>>(Wo, wopl, (size_t)DIMM * DI);
    // 8) out_proj: 256x128 tiles, split-K=2 -> outtmp + part1 (delta dead)
    gemm3ph<128,2><<<dim3(DIMM/128, MM/256, 2), 512, 0, stream>>>(
        (const unsigned short*)xz, 8192, 2048, wopl, DI, DIMM*DI,
        outtmp, part1, DIMM, DI);
    // 9) rmsnorm over (outtmp+part1) -> x planes (fp32 to d_out on last layer)
    if (i < DEPTH - 1)
      rmsnorm_k<true><<<MM, 256, 0, stream>>>(outtmp, part1, rw, nullptr, xpl);
    else
      rmsnorm_k<false><<<MM, 256, 0, stream>>>(outtmp, part1, rw, out, nullptr);
  }
}